// Round 4
// baseline (803.233 us; speedup 1.0000x reference)
//
#include <hip/hip_runtime.h>
#include <hip/hip_bf16.h>
#include <cstdint>

// MupCausalSelfAttention on MI355X (gfx950), bf16 MFMA pipeline.
// B=4, T=2048, C=2048, H=16, Dh=128. muP scale = 1/Dh = 1/128.
//
// ws layout (bf16 elems):
//   qkv  : [8192][6144] (V third unused; V goes straight to vT)  50,331,648
//   vT   : [64 bh][128 d][2048 t]       16,777,216
//   xb/y : [8192][2048] (y overlays xb) 16,777,216
//   wqT  : [6144][2048]                 12,582,912
//   woT  : [2048][2048]                  4,194,304
//   total 100,663,296 elems = 201,326,592 bytes of d_ws.

using f32x4  = __attribute__((ext_vector_type(4))) float;
using u32x4  = __attribute__((ext_vector_type(4))) unsigned int;
using u16x8  = __attribute__((ext_vector_type(8))) unsigned short;
using u16x4  = __attribute__((ext_vector_type(4))) unsigned short;
using bf16x8 = __attribute__((ext_vector_type(8))) __bf16;

__device__ __forceinline__ unsigned short f2bf(float f) {
  unsigned int u = __builtin_bit_cast(unsigned int, f);
  u += 0x7fffu + ((u >> 16) & 1u);   // round-to-nearest-even
  return (unsigned short)(u >> 16);
}
__device__ __forceinline__ unsigned short f2bf_trunc(float f) {
  return (unsigned short)(__builtin_bit_cast(unsigned int, f) >> 16);
}

// async 16B global->LDS DMA (dest is wave-uniform base + lane*16)
__device__ __forceinline__ void async_copy16(const unsigned short* g, unsigned short* l) {
  __builtin_amdgcn_global_load_lds(
      (const __attribute__((address_space(1))) unsigned int*)g,
      (__attribute__((address_space(3))) unsigned int*)l,
      16, 0, 0);
}

// ---------------- cast x fp32 -> bf16, 8 elems/thread ----------------
__global__ __launch_bounds__(256) void cast_x_kernel(const float* __restrict__ x,
                                                     unsigned short* __restrict__ xb) {
  const size_t i = (size_t)blockIdx.x * 256 + threadIdx.x;
  const float* p = x + i * 8;
  f32x4 a = *(const f32x4*)p;
  f32x4 b = *(const f32x4*)(p + 4);
  u16x8 o;
#pragma unroll
  for (int e = 0; e < 4; ++e) { o[e] = f2bf(a[e]); o[e + 4] = f2bf(b[e]); }
  *(u32x4*)(xb + i * 8) = __builtin_bit_cast(u32x4, o);
}

// ---------- W[K][N] fp32 -> WT[N][K] bf16, 64x64 LDS tile ----------
__global__ __launch_bounds__(256) void transpose_cast_w(const float* __restrict__ W,
                                                        unsigned short* __restrict__ WT,
                                                        int K, int N) {
  __shared__ unsigned short tbuf[64 * 68];
  const int tid = threadIdx.x;
  const int k0 = blockIdx.x * 64, n0 = blockIdx.y * 64;
#pragma unroll
  for (int it = 0; it < 4; ++it) {
    int c = it * 256 + tid;
    int kl = c >> 4, n4 = (c & 15) * 4;
    f32x4 v = *(const f32x4*)(W + (size_t)(k0 + kl) * N + n0 + n4);
#pragma unroll
    for (int e = 0; e < 4; ++e) tbuf[(n4 + e) * 68 + kl] = f2bf(v[e]);
  }
  __syncthreads();
#pragma unroll
  for (int it = 0; it < 2; ++it) {
    int c = it * 256 + tid;
    int nl = c >> 3, k8 = (c & 7) * 8;
    u16x4 lo = *(const u16x4*)&tbuf[nl * 68 + k8];
    u16x4 hi = *(const u16x4*)&tbuf[nl * 68 + k8 + 4];
    u16x8 o;
#pragma unroll
    for (int e = 0; e < 4; ++e) { o[e] = lo[e]; o[e + 4] = hi[e]; }
    *(u32x4*)(WT + (size_t)(n0 + nl) * K + k0 + k8) = __builtin_bit_cast(u32x4, o);
  }
}

// ------- C[M,N] = A[M,K] @ BT[N,K]^T + bias, bf16 MFMA 16x16x32 -------
// m97 structure: global_load_lds(16B) staging, unpadded LDS, XOR chunk
// swizzle (2-way max on banks = free, m136). For OUT_BF16 (the QKV GEMM),
// columns n>=4096 (the V third) are written TRANSPOSED straight into
// vT[bh][d][t] as packed 8B stores (C-layout holds 4 consecutive m=t).
template <bool OUT_BF16>
__global__ __launch_bounds__(256) void gemm_bt(const unsigned short* __restrict__ A,
                                               const unsigned short* __restrict__ BT,
                                               const float* __restrict__ bias,
                                               void* __restrict__ Cout,
                                               unsigned short* __restrict__ vTout,
                                               int M, int N, int K) {
  __shared__ unsigned short As[128 * 32];
  __shared__ unsigned short Bs[128 * 32];
  const int tid  = threadIdx.x;
  const int lane = tid & 63;
  const int wave = tid >> 6;
  const int wm = (wave >> 1) * 64;
  const int wn = (wave & 1) * 64;
  const int m0 = blockIdx.x * 128;
  const int n0 = blockIdx.y * 128;
  const int r16  = lane & 15;
  const int quad = lane >> 4;
  const int sw   = quad ^ ((r16 >> 1) & 3);  // fragment chunk swizzle

  const int srow0 = tid >> 2;
  const int g0 = (tid & 3) ^ ((tid >> 3) & 3);

  f32x4 acc[4][4] = {};
  const unsigned short* Ab = A + (size_t)m0 * K;
  const unsigned short* Bb = BT + (size_t)n0 * K;

  for (int k0 = 0; k0 < K; k0 += 32) {
#pragma unroll
    for (int it = 0; it < 2; ++it) {
      const int row = it * 64 + srow0;
      async_copy16(Ab + (size_t)row * K + k0 + g0 * 8, As + (it * 256 + tid) * 8);
      async_copy16(Bb + (size_t)row * K + k0 + g0 * 8, Bs + (it * 256 + tid) * 8);
    }
    __syncthreads();
    bf16x8 af[4], bfr[4];
#pragma unroll
    for (int i = 0; i < 4; ++i)
      af[i] = __builtin_bit_cast(bf16x8,
          *(const u32x4*)(As + ((wm + i * 16 + r16) * 4 + sw) * 8));
#pragma unroll
    for (int j = 0; j < 4; ++j)
      bfr[j] = __builtin_bit_cast(bf16x8,
          *(const u32x4*)(Bs + ((wn + j * 16 + r16) * 4 + sw) * 8));
#pragma unroll
    for (int i = 0; i < 4; ++i)
#pragma unroll
      for (int j = 0; j < 4; ++j)
        acc[i][j] = __builtin_amdgcn_mfma_f32_16x16x32_bf16(af[i], bfr[j], acc[i][j], 0, 0, 0);
    __syncthreads();
  }

#pragma unroll
  for (int j = 0; j < 4; ++j) {
    const int n = n0 + wn + j * 16 + r16;
    const float bv = bias[n];
    bool vregion = false;
    if constexpr (OUT_BF16) vregion = (n >= 4096);  // uniform per j (16-aligned groups)
    if (vregion) {
      const int d = n & 127;
      const int h = (n - 4096) >> 7;
#pragma unroll
      for (int i = 0; i < 4; ++i) {
        const int mr = m0 + wm + i * 16 + quad * 4;
        const int bh = (mr >> 11) * 16 + h;
        u16x4 o4;
#pragma unroll
        for (int r = 0; r < 4; ++r) o4[r] = f2bf(acc[i][j][r] + bv);
        *(u16x4*)(vTout + ((size_t)bh * 128 + d) * 2048 + (mr & 2047)) = o4;
      }
    } else {
#pragma unroll
      for (int i = 0; i < 4; ++i) {
        const int mr = m0 + wm + i * 16 + quad * 4;
#pragma unroll
        for (int r = 0; r < 4; ++r) {
          float v = acc[i][j][r] + bv;
          if constexpr (OUT_BF16)
            ((unsigned short*)Cout)[(size_t)(mr + r) * N + n] = f2bf(v);
          else
            ((float*)Cout)[(size_t)(mr + r) * N + n] = v;
        }
      }
    }
  }
}

// --------------- flash attention v2, causal, muP scale 1/128 ---------------
// Block = 4 waves, 128 q-rows (32/wave as 2 m-tiles). kv tiles of 64 staged
// in LDS via global_load_lds(16B) with XOR chunk swizzle.
// No online max (muP logits O(1), softmax shift-invariant). Softmax body is
// split masked/unmasked on the wave-uniform diagonal test; P uses truncating
// bf16 (error <2^-8, washed by l-normalization).
__global__ __launch_bounds__(256) void attn_kernel(const unsigned short* __restrict__ qkv,
                                                   const unsigned short* __restrict__ vT,
                                                   unsigned short* __restrict__ y) {
  __shared__ unsigned short Ks[64 * 128];    // [kvrow][chunk c]: holds K chunk c^(row&15)
  __shared__ unsigned short Vs[128 * 64];    // [drow][chunk c]: holds vT chunk c^(drow&7)
  __shared__ unsigned short Ps[4][32 * 72];  // per-wave P (C-layout -> A-layout bridge)

  const int tid  = threadIdx.x;
  const int lane = tid & 63;
  const int wave = tid >> 6;
  const int r16  = lane & 15;
  const int quad = lane >> 4;
  const int qt   = 15 - blockIdx.x;          // heavy (large-q) blocks first
  const int q0   = qt * 128;
  const int bh   = blockIdx.y;
  const int b    = bh >> 4, h = bh & 15;
  const int wq0  = q0 + wave * 32;
  unsigned short* pl = Ps[wave];

  // Q A-frags: Q[m=r16][k=kc*32+quad*8+j]
  bf16x8 aq[2][4];
#pragma unroll
  for (int mi = 0; mi < 2; ++mi) {
    const unsigned short* qp = qkv + (size_t)(b * 2048 + wq0 + mi * 16 + r16) * 6144 + h * 128;
#pragma unroll
    for (int kc = 0; kc < 4; ++kc)
      aq[mi][kc] = __builtin_bit_cast(bf16x8, *(const u32x4*)(qp + kc * 32 + quad * 8));
  }

  f32x4 o[2][8] = {};
  float rs_l[2][4] = {};

  const unsigned short* kbase = qkv + (size_t)b * 2048 * 6144 + 2048 + h * 128;
  const unsigned short* vbase = vT + (size_t)bh * 128 * 2048;
  const int ntiles = 2 * qt + 2;
  constexpr float C = 0.0112718764f;  // (1/128)*log2(e)

  for (int t = 0; t < ntiles; ++t) {
    const int kv0 = t * 64;
    // stage K tile: 64 rows x 16 chunks(16B); slot(row,c) <- K chunk c^(row&15)
#pragma unroll
    for (int it = 0; it < 4; ++it) {
      const int slot = it * 256 + tid;
      const int row = slot >> 4, c = slot & 15;
      const int g = c ^ (row & 15);
      async_copy16(kbase + (size_t)(kv0 + row) * 6144 + g * 8, Ks + slot * 8);
    }
    // stage V tile: 128 d-rows x 8 chunks; slot(dr,c) <- vT chunk c^(dr&7)
#pragma unroll
    for (int it = 0; it < 4; ++it) {
      const int slot = it * 256 + tid;
      const int dr = slot >> 3, c = slot & 7;
      const int g = c ^ (dr & 7);
      async_copy16(vbase + (size_t)dr * 2048 + kv0 + g * 8, Vs + slot * 8);
    }
    __syncthreads();

    // S = Q K^T  (B-frag: K[kv=n][d=k], swizzled read from Ks)
    f32x4 s[2][4] = {};
#pragma unroll
    for (int kc = 0; kc < 4; ++kc) {
#pragma unroll
      for (int nt = 0; nt < 4; ++nt) {
        const int krow = nt * 16 + r16;
        const int chunk = kc * 4 + quad;
        bf16x8 bk = __builtin_bit_cast(bf16x8,
            *(const u32x4*)(Ks + (krow * 16 + (chunk ^ (krow & 15))) * 8));
#pragma unroll
        for (int mi = 0; mi < 2; ++mi)
          s[mi][nt] = __builtin_amdgcn_mfma_f32_16x16x32_bf16(aq[mi][kc], bk, s[mi][nt], 0, 0, 0);
      }
    }

    if (kv0 + 64 <= wq0) {  // fully unmasked tile (wave-uniform fast path)
#pragma unroll
      for (int mi = 0; mi < 2; ++mi) {
#pragma unroll
        for (int r = 0; r < 4; ++r) {
          float acc = 0.0f;
#pragma unroll
          for (int nt = 0; nt < 4; ++nt) {
            float e = exp2f(s[mi][nt][r] * C);
            acc += e;
            pl[(mi * 16 + quad * 4 + r) * 72 + nt * 16 + r16] = f2bf_trunc(e);
          }
          rs_l[mi][r] += acc;
        }
      }
    } else {                // diagonal tile: causal mask
#pragma unroll
      for (int mi = 0; mi < 2; ++mi) {
#pragma unroll
        for (int r = 0; r < 4; ++r) {
          const int qg = wq0 + mi * 16 + quad * 4 + r;
          float acc = 0.0f;
#pragma unroll
          for (int nt = 0; nt < 4; ++nt) {
            float e = exp2f(s[mi][nt][r] * C);
            if (kv0 + nt * 16 + r16 > qg) e = 0.0f;
            acc += e;
            pl[(mi * 16 + quad * 4 + r) * 72 + nt * 16 + r16] = f2bf_trunc(e);
          }
          rs_l[mi][r] += acc;
        }
      }
    }

    // O += P V  (A-frag from Ps, B-frag: vT[d=n][kv=k] swizzled from Vs)
#pragma unroll
    for (int kc = 0; kc < 2; ++kc) {
      bf16x8 ap[2];
#pragma unroll
      for (int mi = 0; mi < 2; ++mi)
        ap[mi] = __builtin_bit_cast(bf16x8,
            *(const u32x4*)(pl + (mi * 16 + r16) * 72 + kc * 32 + quad * 8));
#pragma unroll
      for (int d = 0; d < 8; ++d) {
        const int drow = d * 16 + r16;
        const int chunk = kc * 4 + quad;
        bf16x8 bv = __builtin_bit_cast(bf16x8,
            *(const u32x4*)(Vs + (drow * 8 + (chunk ^ (drow & 7))) * 8));
#pragma unroll
        for (int mi = 0; mi < 2; ++mi)
          o[mi][d] = __builtin_amdgcn_mfma_f32_16x16x32_bf16(ap[mi], bv, o[mi][d], 0, 0, 0);
      }
    }
    __syncthreads();
  }

  // finalize: one l-reduction at the end, then normalize + store
#pragma unroll
  for (int mi = 0; mi < 2; ++mi) {
#pragma unroll
    for (int r = 0; r < 4; ++r) {
      float rs = rs_l[mi][r];
#pragma unroll
      for (int off = 8; off >= 1; off >>= 1) rs += __shfl_xor(rs, off);
      const float inv = 1.0f / rs;
      const int qg = wq0 + mi * 16 + quad * 4 + r;
      unsigned short* yp = y + (size_t)(b * 2048 + qg) * 2048 + h * 128;
#pragma unroll
      for (int d = 0; d < 8; ++d)
        yp[d * 16 + r16] = f2bf(o[mi][d][r] * inv);
    }
  }
}

extern "C" void kernel_launch(void* const* d_in, const int* in_sizes, int n_in,
                              void* d_out, int out_size, void* d_ws, size_t ws_size,
                              hipStream_t stream) {
  const float* x     = (const float*)d_in[0];
  const float* W_qkv = (const float*)d_in[1];
  const float* b_qkv = (const float*)d_in[2];
  const float* W_out = (const float*)d_in[3];
  const float* b_out = (const float*)d_in[4];

  unsigned short* ws  = (unsigned short*)d_ws;
  unsigned short* qkv = ws;                   // 50,331,648
  unsigned short* vT  = ws + 50331648;        // 16,777,216
  unsigned short* xb  = ws + 67108864;        // 16,777,216 (y overlays xb)
  unsigned short* wqT = ws + 83886080;        // 12,582,912
  unsigned short* woT = ws + 96468992;        //  4,194,304
  unsigned short* y   = xb;

  cast_x_kernel<<<8192, 256, 0, stream>>>(x, xb);
  transpose_cast_w<<<dim3(32, 96), 256, 0, stream>>>(W_qkv, wqT, 2048, 6144);
  transpose_cast_w<<<dim3(32, 32), 256, 0, stream>>>(W_out, woT, 2048, 2048);
  gemm_bt<true><<<dim3(64, 48), 256, 0, stream>>>(xb, wqT, b_qkv, qkv, vT, 8192, 6144, 2048);
  attn_kernel<<<dim3(16, 64), 256, 0, stream>>>(qkv, vT, y);
  gemm_bt<false><<<dim3(64, 16), 256, 0, stream>>>(y, woT, b_out, d_out, nullptr, 8192, 2048, 2048);
}